// Round 1
// baseline (530.163 us; speedup 1.0000x reference)
//
#include <hip/hip_runtime.h>
#include <math.h>

#define D_MODEL 1024
#define D_FF    4096
#define RANK    128
#define M_ROWS  8192
#define FHALF   (D_FF / 2)   // f-range per split (2 splits -> 256 blocks)

__device__ __forceinline__ float gelu_exact(float v) {
    // nn.GELU() exact: 0.5*v*(1+erf(v/sqrt(2)))
    return 0.5f * v * (1.0f + erff(v * 0.70710678118654752440f));
}

// ---------------------------------------------------------------------------
// Kernel A: t1[m, r] = S[r] * sum_d x[m, d] * U[d, r]
// M=8192, K=1024, N=128.  Grid: M/32 = 256 blocks, 256 threads.
// Per-thread tile: 2 rows x 8 cols.
// ---------------------------------------------------------------------------
__global__ __launch_bounds__(256) void k_t1(
    const float* __restrict__ x, const float* __restrict__ U,
    const float* __restrict__ S, float* __restrict__ t1)
{
    __shared__ __align__(16) float xs[32][36];    // pad 36: float4-aligned rows
    __shared__ __align__(16) float Us[32][132];   // [k][r], pad 132

    const int tid = threadIdx.x;
    const int tx = tid & 15;   // 8 r-cols each
    const int ty = tid >> 4;   // 2 m-rows each
    const int m0 = blockIdx.x * 32;

    float acc[2][8];
#pragma unroll
    for (int i = 0; i < 2; ++i)
#pragma unroll
        for (int j = 0; j < 8; ++j) acc[i][j] = 0.0f;

    for (int d0 = 0; d0 < D_MODEL; d0 += 32) {
        __syncthreads();
#pragma unroll
        for (int it = 0; it < 4; ++it) {          // 32x32 x-tile
            int idx = it * 256 + tid;
            int mm = idx >> 5, dd = idx & 31;
            xs[mm][dd] = x[(size_t)(m0 + mm) * D_MODEL + d0 + dd];
        }
#pragma unroll
        for (int it = 0; it < 16; ++it) {         // 32x128 U-tile
            int idx = it * 256 + tid;
            int dd = idx >> 7, rr = idx & 127;
            Us[dd][rr] = U[(size_t)(d0 + dd) * RANK + rr];
        }
        __syncthreads();

#pragma unroll 2
        for (int k = 0; k < 32; k += 4) {
            float4 a0 = *(const float4*)&xs[2 * ty + 0][k];
            float4 a1 = *(const float4*)&xs[2 * ty + 1][k];
            float av0[4] = {a0.x, a0.y, a0.z, a0.w};
            float av1[4] = {a1.x, a1.y, a1.z, a1.w};
#pragma unroll
            for (int kk = 0; kk < 4; ++kk) {
                float4 b0 = *(const float4*)&Us[k + kk][8 * tx];
                float4 b1 = *(const float4*)&Us[k + kk][8 * tx + 4];
                float bv[8] = {b0.x, b0.y, b0.z, b0.w, b1.x, b1.y, b1.z, b1.w};
#pragma unroll
                for (int j = 0; j < 8; ++j) {
                    acc[0][j] += av0[kk] * bv[j];
                    acc[1][j] += av1[kk] * bv[j];
                }
            }
        }
    }

    float s[8];
#pragma unroll
    for (int j = 0; j < 8; ++j) s[j] = S[8 * tx + j];
#pragma unroll
    for (int i = 0; i < 2; ++i) {
        const int m = m0 + 2 * ty + i;
#pragma unroll
        for (int j = 0; j < 8; ++j)
            t1[(size_t)m * RANK + 8 * tx + j] = acc[i][j] * s[j];
    }
}

// ---------------------------------------------------------------------------
// Kernel BC (fused): for a 64-row tile and an f-range of FHALF:
//   h[m,f]  = gelu(sum_r t1[m,r]*Vfc[f,r] + bfc[f])     (h kept in LDS only)
//   t2p[m,r] = Spj[r] * sum_{f in range} h[m,f]*Upj[f,r]
// Two f-splits (blockIdx.y) write partial t2 buffers, summed in kernel D.
// Grid: (M/64, 2) = 256 blocks, 256 threads. LDS ~92 KB -> 1 block/CU.
// ---------------------------------------------------------------------------
__global__ __launch_bounds__(256) void k_fused(
    const float* __restrict__ t1g, const float* __restrict__ Vfc,
    const float* __restrict__ bfc, const float* __restrict__ Upj,
    const float* __restrict__ Spj, float* __restrict__ t2part)
{
    __shared__ __align__(16) float t1s[64][132];     // [m][r]
    __shared__ __align__(16) float wbuf[128 * 68];   // VfcT [128][68] OR Upj [64][132]
    __shared__ __align__(16) float hs[64][68];       // [m][f-chunk]
    __shared__ __align__(16) float bias_s[FHALF];

    const int tid = threadIdx.x;
    const int tx = tid & 15;
    const int ty = tid >> 4;
    const int m0 = blockIdx.x * 64;
    const int fbeg = blockIdx.y * FHALF;
    float* __restrict__ t2out = t2part + (size_t)blockIdx.y * (M_ROWS * RANK);

    // preload t1 tile (64x128) and this split's bias range
#pragma unroll
    for (int it = 0; it < 32; ++it) {
        int idx = it * 256 + tid;
        int mm = idx >> 7, rr = idx & 127;
        t1s[mm][rr] = t1g[(size_t)(m0 + mm) * RANK + rr];
    }
#pragma unroll
    for (int it = 0; it < FHALF / 256; ++it)
        bias_s[it * 256 + tid] = bfc[fbeg + it * 256 + tid];

    float t2acc[4][8];
#pragma unroll
    for (int i = 0; i < 4; ++i)
#pragma unroll
        for (int j = 0; j < 8; ++j) t2acc[i][j] = 0.0f;

    for (int c = 0; c < FHALF / 64; ++c) {           // 32 chunks of 64 f
        const int f0 = fbeg + c * 64;

        __syncthreads();  // prev stage-3 done with wbuf/hs; initial loads done
        // load Vfc chunk transposed: V[f0+ff][k] -> wbuf[k*68+ff]
#pragma unroll
        for (int it = 0; it < 32; ++it) {
            int idx = it * 256 + tid;
            int ff = idx >> 7, kk = idx & 127;
            wbuf[kk * 68 + ff] = Vfc[(size_t)(f0 + ff) * RANK + kk];
        }
        __syncthreads();

        // stage 2: h tile 64m x 64f, per-thread 4m x 4f, dot over r=128
        float hacc[4][4];
#pragma unroll
        for (int i = 0; i < 4; ++i)
#pragma unroll
            for (int j = 0; j < 4; ++j) hacc[i][j] = 0.0f;

#pragma unroll 2
        for (int k = 0; k < RANK; k += 4) {
            float av[4][4];
#pragma unroll
            for (int i = 0; i < 4; ++i) {
                float4 a = *(const float4*)&t1s[4 * ty + i][k];
                av[i][0] = a.x; av[i][1] = a.y; av[i][2] = a.z; av[i][3] = a.w;
            }
#pragma unroll
            for (int kk = 0; kk < 4; ++kk) {
                float4 b = *(const float4*)&wbuf[(k + kk) * 68 + 4 * tx];
                float bv[4] = {b.x, b.y, b.z, b.w};
#pragma unroll
                for (int i = 0; i < 4; ++i)
#pragma unroll
                    for (int j = 0; j < 4; ++j)
                        hacc[i][j] += av[i][kk] * bv[j];
            }
        }
        // bias + exact gelu, write h tile to LDS
#pragma unroll
        for (int i = 0; i < 4; ++i) {
            float tmp[4];
#pragma unroll
            for (int j = 0; j < 4; ++j) {
                float v = hacc[i][j] + bias_s[c * 64 + 4 * tx + j];
                tmp[j] = gelu_exact(v);
            }
            float4 hv = {tmp[0], tmp[1], tmp[2], tmp[3]};
            *(float4*)&hs[4 * ty + i][4 * tx] = hv;
        }
        __syncthreads();  // hs visible; stage-2 wbuf reads done

        // load Upj chunk: U[f0+ff][r] -> wbuf[ff*132+r]
#pragma unroll
        for (int it = 0; it < 32; ++it) {
            int idx = it * 256 + tid;
            int ff = idx >> 7, rr = idx & 127;
            wbuf[ff * 132 + rr] = Upj[(size_t)(f0 + ff) * RANK + rr];
        }
        __syncthreads();

        // stage 3: t2acc[4m][8r] += h[m,f] * Upj[f,r] over 64 f
#pragma unroll 2
        for (int f = 0; f < 64; f += 4) {
            float av[4][4];
#pragma unroll
            for (int i = 0; i < 4; ++i) {
                float4 a = *(const float4*)&hs[4 * ty + i][f];
                av[i][0] = a.x; av[i][1] = a.y; av[i][2] = a.z; av[i][3] = a.w;
            }
#pragma unroll
            for (int ff = 0; ff < 4; ++ff) {
                float4 b0 = *(const float4*)&wbuf[(f + ff) * 132 + 8 * tx];
                float4 b1 = *(const float4*)&wbuf[(f + ff) * 132 + 8 * tx + 4];
                float bv[8] = {b0.x, b0.y, b0.z, b0.w, b1.x, b1.y, b1.z, b1.w};
#pragma unroll
                for (int i = 0; i < 4; ++i)
#pragma unroll
                    for (int j = 0; j < 8; ++j)
                        t2acc[i][j] += av[i][ff] * bv[j];
            }
        }
    }

    // epilogue: scale by Spj, write partial t2
    float s[8];
#pragma unroll
    for (int j = 0; j < 8; ++j) s[j] = Spj[8 * tx + j];
#pragma unroll
    for (int i = 0; i < 4; ++i) {
        const int m = m0 + 4 * ty + i;
#pragma unroll
        for (int j = 0; j < 8; ++j)
            t2out[(size_t)m * RANK + 8 * tx + j] = t2acc[i][j] * s[j];
    }
}

// ---------------------------------------------------------------------------
// Kernel D: out[m, n] = sum_r (t2a+t2b)[m,r] * Vpj[n,r] + bpj[n]
// M=8192, N=1024, K=128. Grid (M/64, N/64) = 2048 blocks, 256 threads.
// ---------------------------------------------------------------------------
__global__ __launch_bounds__(256) void k_out(
    const float* __restrict__ t2part, const float* __restrict__ Vpj,
    const float* __restrict__ bpj, float* __restrict__ out)
{
    __shared__ __align__(16) float t2s[64][132];   // [m][k]
    __shared__ __align__(16) float VsT[128][68];   // [k][n]

    const int tid = threadIdx.x;
    const int tx = tid & 15, ty = tid >> 4;
    const int m0 = blockIdx.x * 64;
    const int n0 = blockIdx.y * 64;
    const float* __restrict__ t2a = t2part;
    const float* __restrict__ t2b = t2part + (size_t)M_ROWS * RANK;

#pragma unroll
    for (int it = 0; it < 32; ++it) {
        int idx = it * 256 + tid;
        int mm = idx >> 7, kk = idx & 127;
        size_t g = (size_t)(m0 + mm) * RANK + kk;
        t2s[mm][kk] = t2a[g] + t2b[g];
    }
#pragma unroll
    for (int it = 0; it < 32; ++it) {
        int idx = it * 256 + tid;
        int nn = idx >> 7, kk = idx & 127;
        VsT[kk][nn] = Vpj[(size_t)(n0 + nn) * RANK + kk];
    }
    __syncthreads();

    float acc[4][4];
#pragma unroll
    for (int i = 0; i < 4; ++i)
#pragma unroll
        for (int j = 0; j < 4; ++j) acc[i][j] = 0.0f;

#pragma unroll 2
    for (int k = 0; k < RANK; k += 4) {
        float av[4][4];
#pragma unroll
        for (int i = 0; i < 4; ++i) {
            float4 a = *(const float4*)&t2s[4 * ty + i][k];
            av[i][0] = a.x; av[i][1] = a.y; av[i][2] = a.z; av[i][3] = a.w;
        }
#pragma unroll
        for (int kk = 0; kk < 4; ++kk) {
            float4 b = *(const float4*)&VsT[k + kk][4 * tx];
            float bv[4] = {b.x, b.y, b.z, b.w};
#pragma unroll
            for (int i = 0; i < 4; ++i)
#pragma unroll
                for (int j = 0; j < 4; ++j)
                    acc[i][j] += av[i][kk] * bv[j];
        }
    }

    float bv[4];
#pragma unroll
    for (int j = 0; j < 4; ++j) bv[j] = bpj[n0 + 4 * tx + j];
#pragma unroll
    for (int i = 0; i < 4; ++i) {
        float4 o = {acc[i][0] + bv[0], acc[i][1] + bv[1],
                    acc[i][2] + bv[2], acc[i][3] + bv[3]};
        *(float4*)&out[(size_t)(m0 + 4 * ty + i) * D_MODEL + n0 + 4 * tx] = o;
    }
}

extern "C" void kernel_launch(void* const* d_in, const int* in_sizes, int n_in,
                              void* d_out, int out_size, void* d_ws, size_t ws_size,
                              hipStream_t stream) {
    const float* x    = (const float*)d_in[0];
    const float* cfcU = (const float*)d_in[1];
    const float* cfcS = (const float*)d_in[2];
    const float* cfcV = (const float*)d_in[3];
    const float* cfcB = (const float*)d_in[4];
    const float* pjU  = (const float*)d_in[5];
    const float* pjS  = (const float*)d_in[6];
    const float* pjV  = (const float*)d_in[7];
    const float* pjB  = (const float*)d_in[8];
    float* out = (float*)d_out;

    // ws layout: t1 [8192*128] | t2 partials [2][8192*128]  -> 12 MB total
    float* t1  = (float*)d_ws;
    float* t2p = t1 + (size_t)M_ROWS * RANK;

    k_t1   <<<dim3(M_ROWS / 32), 256, 0, stream>>>(x, cfcU, cfcS, t1);
    k_fused<<<dim3(M_ROWS / 64, 2), 256, 0, stream>>>(t1, cfcV, cfcB, pjU, pjS, t2p);
    k_out  <<<dim3(M_ROWS / 64, D_MODEL / 64), 256, 0, stream>>>(t2p, pjV, pjB, out);
}

// Round 2
// 392.226 us; speedup vs baseline: 1.3517x; 1.3517x over previous
//
#include <hip/hip_runtime.h>
#include <math.h>

#define D_MODEL 1024
#define D_FF    4096
#define RANK    128
#define M_ROWS  8192

typedef _Float16 f16;
typedef _Float16 f16x8 __attribute__((ext_vector_type(8)));
typedef float    f32x4 __attribute__((ext_vector_type(4)));

#define MFMA16(a, b, c) __builtin_amdgcn_mfma_f32_16x16x32_f16((a), (b), (c), 0, 0, 0)

__device__ __forceinline__ f16x8 ld8(const f16* p) { return *(const f16x8*)p; }

__device__ __forceinline__ float gelu_exact(float v) {
    return 0.5f * v * (1.0f + erff(v * 0.70710678118654752440f));
}

// ---------------------------------------------------------------------------
// Prep: convert/transpose/scale weights into ws (f16).
//  w1T[r][d] = cfc_U[d][r]*cfc_S[r]   [128][1024]
//  v1 [f][r] = cfc_V[f][r]            [4096][128]
//  w2T[r][f] = cproj_U[f][r]*cproj_S[r] [128][4096]
//  v2 [d][r] = cproj_V[d][r]          [1024][128]
// Total elements: 131072 + 524288 + 524288 + 131072 = 1310720
// ---------------------------------------------------------------------------
__global__ __launch_bounds__(256) void k_prep(
    const float* __restrict__ cfcU, const float* __restrict__ cfcS,
    const float* __restrict__ cfcV, const float* __restrict__ pjU,
    const float* __restrict__ pjS,  const float* __restrict__ pjV,
    f16* __restrict__ w1T, f16* __restrict__ v1,
    f16* __restrict__ w2T, f16* __restrict__ v2)
{
    int i = blockIdx.x * 256 + threadIdx.x;
    if (i < 131072) {                       // w1T
        int r = i >> 10, d = i & 1023;
        w1T[i] = (f16)(cfcU[d * RANK + r] * cfcS[r]);
    } else if (i < 655360) {                // v1 (plain convert)
        int j = i - 131072;
        v1[j] = (f16)cfcV[j];
    } else if (i < 1179648) {               // w2T
        int j = i - 655360;
        int r = j >> 12, f = j & 4095;
        w2T[j] = (f16)(pjU[f * RANK + r] * pjS[r]);
    } else if (i < 1310720) {               // v2 (plain convert)
        int j = i - 1179648;
        v2[j] = (f16)pjV[j];
    }
}

// ---------------------------------------------------------------------------
// Stage 1: t1[m][r] = x[m][:] @ w1T[r][:]^T   (M=8192, N=128, K=1024), f16 out.
// 128 thr = 2 waves; wave = 16 m-rows x 128 r. Grid 256.
// A-frags converted from fp32 x on the fly; B-frags direct global (L2, 256 KB).
// MFMA layouts (guide-verified): A[m=lane&15][k=quad*8+j], B[n=lane&15][k=quad*8+j]
// (k-contiguous), C/D: col=lane&15, row=quad*4+reg.
// ---------------------------------------------------------------------------
__global__ __launch_bounds__(128) void k_t1(
    const float* __restrict__ x, const f16* __restrict__ w1T,
    f16* __restrict__ t1)
{
    const int lane = threadIdx.x & 63;
    const int wv   = threadIdx.x >> 6;
    const int m0   = blockIdx.x * 32 + wv * 16;
    const int c    = lane & 15, q = lane >> 4;

    f32x4 acc[8] = {};
    const float* xrow = x + (size_t)(m0 + c) * D_MODEL;

    for (int kb = 0; kb < 32; ++kb) {
        const float* ap = xrow + kb * 32 + q * 8;
        float4 a0 = *(const float4*)ap;
        float4 a1 = *(const float4*)(ap + 4);
        f16x8 af = { (f16)a0.x, (f16)a0.y, (f16)a0.z, (f16)a0.w,
                     (f16)a1.x, (f16)a1.y, (f16)a1.z, (f16)a1.w };
#pragma unroll
        for (int nt = 0; nt < 8; ++nt) {
            f16x8 bf = ld8(w1T + (size_t)(nt * 16 + c) * D_MODEL + kb * 32 + q * 8);
            acc[nt] = MFMA16(af, bf, acc[nt]);
        }
    }
#pragma unroll
    for (int nt = 0; nt < 8; ++nt)
#pragma unroll
        for (int i2 = 0; i2 < 4; ++i2)
            t1[(size_t)(m0 + q * 4 + i2) * RANK + nt * 16 + c] = (f16)acc[nt][i2];
}

// ---------------------------------------------------------------------------
// Fused stages 2+3: per wave (16 m-rows), loop f-chunks of 64 over this
// split's 2048 f:
//   h(16x64) = gelu(t1(16x128) @ v1_chunk^T + bias)   [MFMA, C-layout regs]
//   -> per-wave LDS round trip (C-layout -> A-layout), NO cross-wave barrier
//   t2(16x128) += h(16x64) @ w2T_chunk^T              [MFMA, acc in regs]
// Spj is folded into w2T. Partial t2 (one per split) written f16.
// 128 thr = 2 waves, 32 m/block. Grid (256, 2). LDS 4.6 KB/block.
// ---------------------------------------------------------------------------
__global__ __launch_bounds__(128) void k_fused(
    const f16* __restrict__ t1, const f16* __restrict__ v1,
    const float* __restrict__ bfc, const f16* __restrict__ w2T,
    f16* __restrict__ t2p)
{
    __shared__ f16 hs[2][16][72];   // per-wave h tile, pad 72 (16B-aligned rows)

    const int lane = threadIdx.x & 63;
    const int wv   = threadIdx.x >> 6;
    const int m0   = blockIdx.x * 32 + wv * 16;
    const int s    = blockIdx.y;
    const int c    = lane & 15, q = lane >> 4;

    // A2 fragments (t1 row block) — loaded once, live in regs across f-loop
    f16x8 a2[4];
#pragma unroll
    for (int kb = 0; kb < 4; ++kb)
        a2[kb] = ld8(t1 + (size_t)(m0 + c) * RANK + kb * 32 + q * 8);

    f32x4 c3[8] = {};

    for (int ch = 0; ch < 32; ++ch) {
        const int f0 = s * 2048 + ch * 64;

        // ---- stage 2: h = t1 @ v1^T  (4 f-tiles x K=128)
        f32x4 c2[4] = {};
#pragma unroll
        for (int nt = 0; nt < 4; ++nt) {
#pragma unroll
            for (int kb = 0; kb < 4; ++kb) {
                f16x8 bf = ld8(v1 + (size_t)(f0 + nt * 16 + c) * RANK + kb * 32 + q * 8);
                c2[nt] = MFMA16(a2[kb], bf, c2[nt]);
            }
        }

        // ---- bias + exact gelu, write h into per-wave LDS (C-layout scatter)
#pragma unroll
        for (int nt = 0; nt < 4; ++nt) {
            float b = bfc[f0 + nt * 16 + c];
#pragma unroll
            for (int i2 = 0; i2 < 4; ++i2) {
                float v = c2[nt][i2] + b;
                hs[wv][q * 4 + i2][nt * 16 + c] = (f16)gelu_exact(v);
            }
        }
        // same-wave DS ops execute in order; fence compiler + drain lgkm only
        asm volatile("s_waitcnt lgkmcnt(0)" ::: "memory");

        // ---- stage 3: t2 += h @ w2T^T  (A from LDS in A-layout, 8 r-tiles)
#pragma unroll
        for (int kb2 = 0; kb2 < 2; ++kb2) {
            f16x8 a3 = *(const f16x8*)&hs[wv][c][kb2 * 32 + q * 8];
#pragma unroll
            for (int rt = 0; rt < 8; ++rt) {
                f16x8 bf = ld8(w2T + (size_t)(rt * 16 + c) * D_FF + f0 + kb2 * 32 + q * 8);
                c3[rt] = MFMA16(a3, bf, c3[rt]);
            }
        }
        asm volatile("s_waitcnt lgkmcnt(0)" ::: "memory");
    }

    // epilogue: write f16 partial (scale already folded into w2T)
    f16* o = t2p + (size_t)s * (M_ROWS * RANK);
#pragma unroll
    for (int rt = 0; rt < 8; ++rt)
#pragma unroll
        for (int i2 = 0; i2 < 4; ++i2)
            o[(size_t)(m0 + q * 4 + i2) * RANK + rt * 16 + c] = (f16)c3[rt][i2];
}

// ---------------------------------------------------------------------------
// Stage 4: out[m][d] = (t2p0+t2p1)[m][:] @ v2[d][:]^T + bpj[d], fp32 out.
// 256 thr = 4 waves; block = 64 m x 256 d. Grid (128, 4).
// ---------------------------------------------------------------------------
__global__ __launch_bounds__(256) void k_out(
    const f16* __restrict__ t2p, const f16* __restrict__ v2,
    const float* __restrict__ bpj, float* __restrict__ out)
{
    const int lane = threadIdx.x & 63;
    const int wv   = threadIdx.x >> 6;
    const int m0   = blockIdx.x * 64 + wv * 16;
    const int n0   = blockIdx.y * 256;
    const int c    = lane & 15, q = lane >> 4;

    // A-frags: fp32 sum of the two f16 partials, re-rounded to f16
    f16x8 a[4];
#pragma unroll
    for (int kb = 0; kb < 4; ++kb) {
        const size_t off = (size_t)(m0 + c) * RANK + kb * 32 + q * 8;
        f16x8 p0 = ld8(t2p + off);
        f16x8 p1 = ld8(t2p + (size_t)(M_ROWS * RANK) + off);
#pragma unroll
        for (int e = 0; e < 8; ++e)
            a[kb][e] = (f16)((float)p0[e] + (float)p1[e]);
    }

    f32x4 acc[16] = {};
#pragma unroll
    for (int nt = 0; nt < 16; ++nt)
#pragma unroll
        for (int kb = 0; kb < 4; ++kb) {
            f16x8 bf = ld8(v2 + (size_t)(n0 + nt * 16 + c) * RANK + kb * 32 + q * 8);
            acc[nt] = MFMA16(a[kb], bf, acc[nt]);
        }

#pragma unroll
    for (int nt = 0; nt < 16; ++nt) {
        float b = bpj[n0 + nt * 16 + c];
#pragma unroll
        for (int i2 = 0; i2 < 4; ++i2)
            out[(size_t)(m0 + q * 4 + i2) * D_MODEL + n0 + nt * 16 + c] =
                acc[nt][i2] + b;
    }
}

extern "C" void kernel_launch(void* const* d_in, const int* in_sizes, int n_in,
                              void* d_out, int out_size, void* d_ws, size_t ws_size,
                              hipStream_t stream) {
    const float* x    = (const float*)d_in[0];
    const float* cfcU = (const float*)d_in[1];
    const float* cfcS = (const float*)d_in[2];
    const float* cfcV = (const float*)d_in[3];
    const float* cfcB = (const float*)d_in[4];
    const float* pjU  = (const float*)d_in[5];
    const float* pjS  = (const float*)d_in[6];
    const float* pjV  = (const float*)d_in[7];
    const float* pjB  = (const float*)d_in[8];
    float* out = (float*)d_out;

    // ws layout (f16 elements), total 8.5 MB:
    //  t1  [8192*128]            @ 0
    //  t2p [2][8192*128]         @ 1048576
    //  w1T [128*1024]            @ 3145728
    //  v1  [4096*128]            @ 3276800
    //  w2T [128*4096]            @ 3801088
    //  v2  [1024*128]            @ 4325376
    f16* wsf = (f16*)d_ws;
    f16* t1  = wsf;
    f16* t2p = wsf + 1048576;
    f16* w1T = wsf + 3145728;
    f16* v1  = wsf + 3276800;
    f16* w2T = wsf + 3801088;
    f16* v2  = wsf + 4325376;

    k_prep <<<dim3(5120), 256, 0, stream>>>(cfcU, cfcS, cfcV, pjU, pjS, pjV,
                                            w1T, v1, w2T, v2);
    k_t1   <<<dim3(M_ROWS / 32), 128, 0, stream>>>(x, w1T, t1);
    k_fused<<<dim3(M_ROWS / 32, 2), 128, 0, stream>>>(t1, v1, cfcB, w2T, t2p);
    k_out  <<<dim3(M_ROWS / 64, D_MODEL / 256), 256, 0, stream>>>(t2p, v2, pjB, out);
}

// Round 5
// 267.584 us; speedup vs baseline: 1.9813x; 1.4658x over previous
//
#include <hip/hip_runtime.h>
#include <math.h>

#define D_MODEL 1024
#define D_FF    4096
#define RANK    128
#define M_ROWS  8192

typedef _Float16 f16;
typedef _Float16 f16x8 __attribute__((ext_vector_type(8)));
typedef float    f32x4 __attribute__((ext_vector_type(4)));

#define MFMA16(a, b, c) __builtin_amdgcn_mfma_f32_16x16x32_f16((a), (b), (c), 0, 0, 0)

__device__ __forceinline__ f16x8 ld8(const f16* p) { return *(const f16x8*)p; }

__device__ __forceinline__ float gelu_exact(float v) {
    return 0.5f * v * (1.0f + erff(v * 0.70710678118654752440f));
}

// ---------------------------------------------------------------------------
// Prep (verbatim R2, proven): convert/transpose/scale weights into ws (f16).
//  w1T[r][d] = cfc_U[d][r]*cfc_S[r]     [128][1024]
//  v1 [f][r] = cfc_V[f][r]              [4096][128]
//  w2T[r][f] = cproj_U[f][r]*cproj_S[r] [128][4096]
//  v2 [d][r] = cproj_V[d][r]            [1024][128]
// ---------------------------------------------------------------------------
__global__ __launch_bounds__(256) void k_prep(
    const float* __restrict__ cfcU, const float* __restrict__ cfcS,
    const float* __restrict__ cfcV, const float* __restrict__ pjU,
    const float* __restrict__ pjS,  const float* __restrict__ pjV,
    f16* __restrict__ w1T, f16* __restrict__ v1,
    f16* __restrict__ w2T, f16* __restrict__ v2)
{
    int i = blockIdx.x * 256 + threadIdx.x;
    if (i < 131072) {
        int r = i >> 10, d = i & 1023;
        w1T[i] = (f16)(cfcU[d * RANK + r] * cfcS[r]);
    } else if (i < 655360) {
        int j = i - 131072;
        v1[j] = (f16)cfcV[j];
    } else if (i < 1179648) {
        int j = i - 655360;
        int r = j >> 12, f = j & 4095;
        w2T[j] = (f16)(pjU[f * RANK + r] * pjS[r]);
    } else if (i < 1310720) {
        int j = i - 1179648;
        v2[j] = (f16)pjV[j];
    }
}

// ---------------------------------------------------------------------------
// Stage 1 (verbatim R2, proven): t1[m][r] = x[m][:] @ w1T[r][:]^T, f16 out.
// 128 thr = 2 waves; wave = 16 m-rows x 128 r, full K=1024. Grid 256.
// ---------------------------------------------------------------------------
__global__ __launch_bounds__(128) void k_t1(
    const float* __restrict__ x, const f16* __restrict__ w1T,
    f16* __restrict__ t1)
{
    const int lane = threadIdx.x & 63;
    const int wv   = threadIdx.x >> 6;
    const int m0   = blockIdx.x * 32 + wv * 16;
    const int c    = lane & 15, q = lane >> 4;

    f32x4 acc[8] = {};
    const float* xrow = x + (size_t)(m0 + c) * D_MODEL;

    for (int kb = 0; kb < 32; ++kb) {
        const float* ap = xrow + kb * 32 + q * 8;
        float4 a0 = *(const float4*)ap;
        float4 a1 = *(const float4*)(ap + 4);
        f16x8 af = { (f16)a0.x, (f16)a0.y, (f16)a0.z, (f16)a0.w,
                     (f16)a1.x, (f16)a1.y, (f16)a1.z, (f16)a1.w };
#pragma unroll
        for (int nt = 0; nt < 8; ++nt) {
            f16x8 bf = ld8(w1T + (size_t)(nt * 16 + c) * D_MODEL + kb * 32 + q * 8);
            acc[nt] = MFMA16(af, bf, acc[nt]);
        }
    }
#pragma unroll
    for (int nt = 0; nt < 8; ++nt)
#pragma unroll
        for (int i2 = 0; i2 < 4; ++i2)
            t1[(size_t)(m0 + q * 4 + i2) * RANK + nt * 16 + c] = (f16)acc[nt][i2];
}

#define RED_STORE(buf, acc)                                            \
    _Pragma("unroll") for (int rt = 0; rt < 8; ++rt)                   \
    _Pragma("unroll") for (int i2 = 0; i2 < 4; ++i2)                   \
        (buf)[q * 4 + i2][rt * 16 + c] = (acc)[rt][i2];
#define RED_ADD(buf, acc)                                              \
    _Pragma("unroll") for (int rt = 0; rt < 8; ++rt)                   \
    _Pragma("unroll") for (int i2 = 0; i2 < 4; ++i2)                   \
        (acc)[rt][i2] += (buf)[q * 4 + i2][rt * 16 + c];

// ---------------------------------------------------------------------------
// Fused stages 2+3. R2 body with two audited deltas:
//  (1) explicit batched fragment loads (R2's VGPR_Count=48 serialized the 16
//      independent L2 loads per stage -> ~19k cyc/chunk; batching + lb(128,2)
//      lets them all fly, and w2T frags are issued BEFORE gelu to overlap it)
//  (2) 2 waves share one m-tile; wave wv takes 16 of the split's 32 chunks;
//      minimal 2-wave reduce (1 store / 1 barrier / 1 add).
// Per-wave hs round-trip + asm barriers: UNCHANGED from proven R2.
// Grid (512, 2) x 2 waves = 2048 waves.
// ---------------------------------------------------------------------------
__global__ __launch_bounds__(128, 2) void k_fused(
    const f16* __restrict__ t1, const f16* __restrict__ v1,
    const float* __restrict__ bfc, const f16* __restrict__ w2T,
    f16* __restrict__ t2p)
{
    __shared__ __align__(16) f16 hs[2][16][72];   // per-wave h tile
    __shared__ float red[16][132];                // 2-wave reduction buffer

    const int lane = threadIdx.x & 63;
    const int wv   = threadIdx.x >> 6;
    const int m0   = blockIdx.x * 16;
    const int s    = blockIdx.y;
    const int c    = lane & 15, q = lane >> 4;

    // A2 fragments (t1 rows) — both waves load the same 16 rows
    f16x8 a2[4];
#pragma unroll
    for (int kb = 0; kb < 4; ++kb)
        a2[kb] = ld8(t1 + (size_t)(m0 + c) * RANK + kb * 32 + q * 8);

    f32x4 c3[8] = {};

#pragma unroll 1
    for (int ch = 0; ch < 16; ++ch) {
        const int f0 = s * 2048 + (wv * 16 + ch) * 64;

        // ---- stage 2: batch-load all 16 v1 frags, then 16 MFMAs
        f16x8 bf2[4][4];
#pragma unroll
        for (int nt = 0; nt < 4; ++nt)
#pragma unroll
            for (int kb = 0; kb < 4; ++kb)
                bf2[nt][kb] = ld8(v1 + (size_t)(f0 + nt * 16 + c) * RANK + kb * 32 + q * 8);

        f32x4 c2[4] = {};
#pragma unroll
        for (int nt = 0; nt < 4; ++nt)
#pragma unroll
            for (int kb = 0; kb < 4; ++kb)
                c2[nt] = MFMA16(a2[kb], bf2[nt][kb], c2[nt]);

        // ---- issue stage-3 B frags now (independent of hs; overlaps gelu)
        f16x8 bf3[2][8];
#pragma unroll
        for (int kb2 = 0; kb2 < 2; ++kb2)
#pragma unroll
            for (int rt = 0; rt < 8; ++rt)
                bf3[kb2][rt] = ld8(w2T + (size_t)(rt * 16 + c) * D_FF + f0 + kb2 * 32 + q * 8);

        // ---- bias + exact gelu -> per-wave LDS (C-layout scatter)
#pragma unroll
        for (int nt = 0; nt < 4; ++nt) {
            float b = bfc[f0 + nt * 16 + c];
#pragma unroll
            for (int i2 = 0; i2 < 4; ++i2)
                hs[wv][q * 4 + i2][nt * 16 + c] = (f16)gelu_exact(c2[nt][i2] + b);
        }
        // cross-lane RAW inside the wave: compiler barrier + drain DS queue
        asm volatile("s_waitcnt lgkmcnt(0)" ::: "memory");

        // ---- stage 3: t2 += h @ w2T^T  (A from LDS in A-layout)
#pragma unroll
        for (int kb2 = 0; kb2 < 2; ++kb2) {
            f16x8 a3 = *(const f16x8*)&hs[wv][c][kb2 * 32 + q * 8];
#pragma unroll
            for (int rt = 0; rt < 8; ++rt)
                c3[rt] = MFMA16(a3, bf3[kb2][rt], c3[rt]);
        }
        // keep next iteration's hs writes behind this iteration's reads
        asm volatile("s_waitcnt lgkmcnt(0)" ::: "memory");
    }

    // ---- minimal 2-wave reduce: wave1 stores, wave0 adds and writes slice s
    if (wv == 1) { RED_STORE(red, c3) }
    __syncthreads();
    if (wv == 0) {
        RED_ADD(red, c3)
        f16* o = t2p + (size_t)s * (M_ROWS * RANK);
#pragma unroll
        for (int rt = 0; rt < 8; ++rt)
#pragma unroll
            for (int i2 = 0; i2 < 4; ++i2)
                o[(size_t)(m0 + q * 4 + i2) * RANK + rt * 16 + c] = (f16)c3[rt][i2];
    }
}

// ---------------------------------------------------------------------------
// Stage 4 (verbatim R2, proven): out = (t2p0+t2p1) @ v2^T + bpj, fp32 out.
// 256 thr = 4 waves; block = 64 m x 256 d. Grid (128, 4).
// ---------------------------------------------------------------------------
__global__ __launch_bounds__(256) void k_out(
    const f16* __restrict__ t2p, const f16* __restrict__ v2,
    const float* __restrict__ bpj, float* __restrict__ out)
{
    const int lane = threadIdx.x & 63;
    const int wv   = threadIdx.x >> 6;
    const int m0   = blockIdx.x * 64 + wv * 16;
    const int n0   = blockIdx.y * 256;
    const int c    = lane & 15, q = lane >> 4;

    f16x8 a[4];
#pragma unroll
    for (int kb = 0; kb < 4; ++kb) {
        const size_t off = (size_t)(m0 + c) * RANK + kb * 32 + q * 8;
        f16x8 p0 = ld8(t2p + off);
        f16x8 p1 = ld8(t2p + (size_t)(M_ROWS * RANK) + off);
#pragma unroll
        for (int e = 0; e < 8; ++e)
            a[kb][e] = (f16)((float)p0[e] + (float)p1[e]);
    }

    f32x4 acc[16] = {};
#pragma unroll
    for (int nt = 0; nt < 16; ++nt)
#pragma unroll
        for (int kb = 0; kb < 4; ++kb) {
            f16x8 bf = ld8(v2 + (size_t)(n0 + nt * 16 + c) * RANK + kb * 32 + q * 8);
            acc[nt] = MFMA16(a[kb], bf, acc[nt]);
        }

#pragma unroll
    for (int nt = 0; nt < 16; ++nt) {
        float b = bpj[n0 + nt * 16 + c];
#pragma unroll
        for (int i2 = 0; i2 < 4; ++i2)
            out[(size_t)(m0 + q * 4 + i2) * D_MODEL + n0 + nt * 16 + c] =
                acc[nt][i2] + b;
    }
}

extern "C" void kernel_launch(void* const* d_in, const int* in_sizes, int n_in,
                              void* d_out, int out_size, void* d_ws, size_t ws_size,
                              hipStream_t stream) {
    const float* x    = (const float*)d_in[0];
    const float* cfcU = (const float*)d_in[1];
    const float* cfcS = (const float*)d_in[2];
    const float* cfcV = (const float*)d_in[3];
    const float* cfcB = (const float*)d_in[4];
    const float* pjU  = (const float*)d_in[5];
    const float* pjS  = (const float*)d_in[6];
    const float* pjV  = (const float*)d_in[7];
    const float* pjB  = (const float*)d_in[8];
    float* out = (float*)d_out;

    // ws layout (f16 elements), verbatim R2 (proven), ~8.9 MB total:
    f16* wsf = (f16*)d_ws;
    f16* t1  = wsf;                 // [8192*128]
    f16* t2p = wsf + 1048576;       // [2][8192*128]
    f16* w1T = wsf + 3145728;       // [128*1024]
    f16* v1  = wsf + 3276800;       // [4096*128]
    f16* w2T = wsf + 3801088;       // [128*4096]
    f16* v2  = wsf + 4325376;       // [1024*128]

    k_prep <<<dim3(5120), 256, 0, stream>>>(cfcU, cfcS, cfcV, pjU, pjS, pjV,
                                            w1T, v1, w2T, v2);
    k_t1   <<<dim3(M_ROWS / 32), 128, 0, stream>>>(x, w1T, t1);
    k_fused<<<dim3(M_ROWS / 16, 2), 128, 0, stream>>>(t1, v1, cfcB, w2T, t2p);
    k_out  <<<dim3(M_ROWS / 64, D_MODEL / 256), 256, 0, stream>>>(t2p, v2, pjB, out);
}